// Round 1
// baseline (1608.744 us; speedup 1.0000x reference)
//
#include <hip/hip_runtime.h>
#include <math.h>

#define IMG 14
#define HO 15
#define LBL 21
#define MIX 5
#define LM 105   // LBL*MIX

// ---------------- generic 3x3 conv (pad = dil), relu ----------------
__global__ void conv3x3_relu(const float* __restrict__ in, const float* __restrict__ w,
                             const float* __restrict__ bias, float* __restrict__ out,
                             int Cin, int Cout, int H, int W, int dil) {
    int idx = blockIdx.x * blockDim.x + threadIdx.x;
    int total = 2 * Cout * H * W;
    if (idx >= total) return;
    int x = idx % W; int t = idx / W;
    int y = t % H; t /= H;
    int o = t % Cout; int b = t / Cout;
    const float* ip = in + (size_t)b * Cin * H * W;
    const float* wp = w + (size_t)o * Cin * 9;
    float acc = bias[o];
    for (int c = 0; c < Cin; ++c) {
        const float* ic = ip + (size_t)c * H * W;
        const float* wc = wp + c * 9;
#pragma unroll
        for (int ky = 0; ky < 3; ++ky) {
            int yy = y + (ky - 1) * dil;
            if (yy < 0 || yy >= H) continue;
#pragma unroll
            for (int kx = 0; kx < 3; ++kx) {
                int xx = x + (kx - 1) * dil;
                if (xx < 0 || xx >= W) continue;
                acc += ic[yy * W + xx] * wc[ky * 3 + kx];
            }
        }
    }
    out[idx] = fmaxf(acc, 0.f);
}

// ---------------- 2x2 maxpool stride 2 ----------------
__global__ void maxpool2k(const float* __restrict__ in, float* __restrict__ out,
                          int C, int Hi, int Ho) {
    int idx = blockIdx.x * blockDim.x + threadIdx.x;
    int total = 2 * C * Ho * Ho;
    if (idx >= total) return;
    int x = idx % Ho; int t = idx / Ho;
    int y = t % Ho; t /= Ho;
    int c = t % C; int b = t / C;
    const float* p = in + (((size_t)b * C + c) * Hi + 2 * y) * Hi + 2 * x;
    out[idx] = fmaxf(fmaxf(p[0], p[1]), fmaxf(p[Hi], p[Hi + 1]));
}

// ---------------- matvec with strided weight tap ----------------
// out[b,o] = act( sum_c w[(o*Cin+c)*S + F] * in[b,c] + bias[o] )
// ACT: 0=none, 1=relu, 2=sigmoid. One 64-lane wave per output.
template <int ACT>
__global__ void matvec(const float* __restrict__ in, const float* __restrict__ w,
                       const float* __restrict__ bias, float* __restrict__ out,
                       int Cin, int Cout, int S, int F) {
    int wid = (blockIdx.x * blockDim.x + threadIdx.x) >> 6;
    int lane = threadIdx.x & 63;
    if (wid >= 2 * Cout) return;
    int b = wid / Cout, o = wid % Cout;
    const float* ip = in + (size_t)b * Cin;
    float acc = 0.f;
    for (int c = lane; c < Cin; c += 64)
        acc += w[(size_t)(o * (size_t)Cin + c) * S + F] * ip[c];
#pragma unroll
    for (int off = 32; off; off >>= 1) acc += __shfl_xor(acc, off);
    if (lane == 0) {
        acc += bias[o];
        if (ACT == 1) acc = fmaxf(acc, 0.f);
        if (ACT == 2) acc = 1.f / (1.f + expf(-acc));
        out[(size_t)b * Cout + o] = acc;
    }
}

// ---------------- locally-connected conv, collapsed ----------------
// h1[b,o,i,j] = sum_c v[b,c] * sum_{s,t in 14x14 window} wl[i,j,o,c,s,t] + bl[o,i,j]
// One wave per (o,i,j): 21*15*15 = 4725 waves.
__global__ void localconv(const float* __restrict__ wl, const float* __restrict__ bl,
                          const float* __restrict__ v, float* __restrict__ h1) {
    int wid = (blockIdx.x * blockDim.x + threadIdx.x) >> 6;
    int lane = threadIdx.x & 63;
    if (wid >= LBL * HO * HO) return;
    int j = wid % HO; int t1 = wid / HO;
    int i = t1 % HO; int o = t1 / HO;
    int s0 = 25 - i, t0 = 25 - j;           // 14 valid taps each axis
    size_t base_ij = ((size_t)(i * HO + j) * LBL + o) * LBL;
    float acc0 = 0.f, acc1 = 0.f;
    for (int c = 0; c < LBL; ++c) {
        const float* p = wl + (base_ij + c) * 2500 + s0 * 50 + t0;
        float part = 0.f;
        for (int e = lane; e < 196; e += 64) {
            int s = e / 14, t = e % 14;
            part += p[s * 50 + t];
        }
        acc0 += v[c] * part;
        acc1 += v[LBL + c] * part;
    }
#pragma unroll
    for (int off = 32; off; off >>= 1) {
        acc0 += __shfl_xor(acc0, off);
        acc1 += __shfl_xor(acc1, off);
    }
    if (lane == 0) {
        float bv = bl[(o * HO + i) * HO + j];
        h1[((0 * LBL + o) * HO + i) * HO + j] = acc0 + bv;
        h1[((1 * LBL + o) * HO + i) * HO + j] = acc1 + bv;
    }
}

// ---------------- channel mix wa ----------------
__global__ void mix_wa(const float* __restrict__ h1, const float* __restrict__ wa,
                       const float* __restrict__ ba, float* __restrict__ h2) {
    int idx = blockIdx.x * blockDim.x + threadIdx.x;
    int total = 2 * LBL * HO * HO;
    if (idx >= total) return;
    int pix = idx % (HO * HO); int t = idx / (HO * HO);
    int o = t % LBL; int b = t / LBL;
    float acc = ba[o];
    for (int c = 0; c < LBL; ++c)
        acc += wa[o * LBL + c] * h1[((size_t)b * LBL + c) * (HO * HO) + pix];
    h2[idx] = acc;
}

// ---------------- conv3d collapsed to 9x9 2-D conv on slice kw=10 ----------------
// h3[b,o,i,j] = sum_{c,di,dj} h2[b,c,i+di-4,j+dj-4] * wm[o,c,di,dj,10] + bm[o]
// Block per (b,o): 210 blocks, 256 threads (225 active outputs).
__global__ void conv9x9(const float* __restrict__ h2, const float* __restrict__ wm,
                        const float* __restrict__ bm, float* __restrict__ h3) {
    __shared__ float sh[LBL * HO * HO];
    int b = blockIdx.x / LM, o = blockIdx.x % LM;
    for (int k = threadIdx.x; k < LBL * HO * HO; k += 256)
        sh[k] = h2[(size_t)b * LBL * HO * HO + k];
    __syncthreads();
    int tid = threadIdx.x;
    if (tid >= HO * HO) return;
    int i = tid / HO, j = tid % HO;
    float acc = bm[o];
    for (int c = 0; c < LBL; ++c) {
        const float* wp = wm + ((size_t)(o * LBL + c) * 81) * LBL + 10;
#pragma unroll
        for (int di = 0; di < 9; ++di) {
            int y = i + di - 4;
            if (y < 0 || y >= HO) continue;
#pragma unroll
            for (int dj = 0; dj < 9; ++dj) {
                int x = j + dj - 4;
                if (x < 0 || x >= HO) continue;
                acc += sh[(c * HO + y) * HO + x] * wp[(size_t)(di * 9 + dj) * LBL];
            }
        }
    }
    h3[((size_t)b * LM + o) * (HO * HO) + tid] = acc;
}

// ---------------- wb mix + block-min(5) + softmax(105) ----------------
// Block per (b,i,k): 2*15*3 = 90 blocks, 128 threads (o in [0,105)).
__global__ void final_k(const float* __restrict__ h3, const float* __restrict__ wbw,
                        const float* __restrict__ bbv, float* __restrict__ out) {
    __shared__ float sv[LM];
    __shared__ float s_mx, s_sum;
    int blk = blockIdx.x;
    int k = blk % 3; int t = blk / 3; int i = t % HO; int b = t / HO;
    int o = threadIdx.x;
    if (o < LM) {
        float mn = 3.4e38f;
        for (int mm = 0; mm < MIX; ++mm) {
            int j = mm * 3 + k;
            float acc = bbv[o];
            const float* hp = h3 + (size_t)b * LM * HO * HO + i * HO + j;
            const float* wp = wbw + o * LM;
            for (int c = 0; c < LM; ++c) acc += wp[c] * hp[(size_t)c * HO * HO];
            mn = fminf(mn, acc);
        }
        sv[o] = mn;
    }
    __syncthreads();
    if (threadIdx.x < 64) {
        int lane = threadIdx.x;
        float m = -3.4e38f;
        for (int c = lane; c < LM; c += 64) m = fmaxf(m, sv[c]);
#pragma unroll
        for (int off = 32; off; off >>= 1) m = fmaxf(m, __shfl_xor(m, off));
        if (lane == 0) s_mx = m;
    }
    __syncthreads();
    if (o < LM) sv[o] = expf(sv[o] - s_mx);
    __syncthreads();
    if (threadIdx.x < 64) {
        int lane = threadIdx.x;
        float s = 0.f;
        for (int c = lane; c < LM; c += 64) s += sv[c];
#pragma unroll
        for (int off = 32; off; off >>= 1) s += __shfl_xor(s, off);
        if (lane == 0) s_sum = s;
    }
    __syncthreads();
    if (o < LM) out[(((size_t)b * LM + o) * HO + i) * 3 + k] = sv[o] / s_sum;
}

extern "C" void kernel_launch(void* const* d_in, const int* in_sizes, int n_in,
                              void* d_out, int out_size, void* d_ws, size_t ws_size,
                              hipStream_t stream) {
    const float* x = (const float*)d_in[0];
    const float* w[14]; const float* bs[14];
    for (int i = 1; i <= 13; ++i) {
        w[i]  = (const float*)d_in[2 * i - 1];
        bs[i] = (const float*)d_in[2 * i];
    }
    const float* wf1 = (const float*)d_in[27]; const float* bf1 = (const float*)d_in[28];
    const float* wf2 = (const float*)d_in[29]; const float* bf2 = (const float*)d_in[30];
    const float* wf3 = (const float*)d_in[31]; const float* bf3 = (const float*)d_in[32];
    const float* wl  = (const float*)d_in[33]; const float* bl  = (const float*)d_in[34];
    const float* wa  = (const float*)d_in[35]; const float* ba  = (const float*)d_in[36];
    const float* wm  = (const float*)d_in[37]; const float* bm  = (const float*)d_in[38];
    const float* wb  = (const float*)d_in[39]; const float* bb  = (const float*)d_in[40];

    float* wsf = (float*)d_ws;
    float* A  = wsf;
    float* B  = wsf + 26624;
    float* v  = wsf + 53248;           // 42 sigmoid scalars
    float* h1 = wsf + 53376;           // 9450
    float* h2 = wsf + 62848;           // 9450
    float* h3 = wsf + 72320;           // 47250

    auto cdiv = [](int a, int b) { return (a + b - 1) / b; };

    // VGG trunk (spatial part)
    conv3x3_relu<<<cdiv(2 * 64 * 196, 256), 256, 0, stream>>>(x, w[1], bs[1], A, 3, 64, 14, 14, 1);
    conv3x3_relu<<<cdiv(2 * 64 * 196, 256), 256, 0, stream>>>(A, w[2], bs[2], B, 64, 64, 14, 14, 1);
    maxpool2k<<<cdiv(2 * 64 * 49, 256), 256, 0, stream>>>(B, A, 64, 14, 7);
    conv3x3_relu<<<cdiv(2 * 128 * 49, 256), 256, 0, stream>>>(A, w[3], bs[3], B, 64, 128, 7, 7, 1);
    conv3x3_relu<<<cdiv(2 * 128 * 49, 256), 256, 0, stream>>>(B, w[4], bs[4], A, 128, 128, 7, 7, 1);
    maxpool2k<<<cdiv(2 * 128 * 9, 256), 256, 0, stream>>>(A, B, 128, 7, 3);
    conv3x3_relu<<<cdiv(2 * 256 * 9, 256), 256, 0, stream>>>(B, w[5], bs[5], A, 128, 256, 3, 3, 1);
    conv3x3_relu<<<cdiv(2 * 256 * 9, 256), 256, 0, stream>>>(A, w[6], bs[6], B, 256, 256, 3, 3, 1);
    conv3x3_relu<<<cdiv(2 * 256 * 9, 256), 256, 0, stream>>>(B, w[7], bs[7], A, 256, 256, 3, 3, 1);
    maxpool2k<<<cdiv(2 * 256, 256), 256, 0, stream>>>(A, B, 256, 3, 1);

    // 1x1-spatial layers: center-tap matvecs (S = kernel elems, F = center index)
    matvec<1><<<cdiv(2 * 512, 4), 256, 0, stream>>>(B, w[8],  bs[8],  A, 256, 512, 9, 4);
    matvec<1><<<cdiv(2 * 512, 4), 256, 0, stream>>>(A, w[9],  bs[9],  B, 512, 512, 9, 4);
    matvec<1><<<cdiv(2 * 512, 4), 256, 0, stream>>>(B, w[10], bs[10], A, 512, 512, 9, 4);
    matvec<1><<<cdiv(2 * 512, 4), 256, 0, stream>>>(A, w[11], bs[11], B, 512, 512, 9, 4);
    matvec<1><<<cdiv(2 * 512, 4), 256, 0, stream>>>(B, w[12], bs[12], A, 512, 512, 9, 4);
    matvec<1><<<cdiv(2 * 512, 4), 256, 0, stream>>>(A, w[13], bs[13], B, 512, 512, 9, 4);
    matvec<1><<<cdiv(2 * 4096, 4), 256, 0, stream>>>(B, wf1, bf1, A, 512, 4096, 49, 24);
    matvec<1><<<cdiv(2 * 4096, 4), 256, 0, stream>>>(A, wf2, bf2, B, 4096, 4096, 1, 0);
    matvec<2><<<cdiv(2 * LBL, 4), 256, 0, stream>>>(B, wf3, bf3, v, 4096, LBL, 1, 0);

    // collapsed locally-connected conv
    localconv<<<cdiv(LBL * HO * HO, 4), 256, 0, stream>>>(wl, bl, v, h1);
    // wa channel mix
    mix_wa<<<cdiv(2 * LBL * HO * HO, 256), 256, 0, stream>>>(h1, wa, ba, h2);
    // conv3d -> 9x9 conv on wm[...,10]
    conv9x9<<<2 * LM, 256, 0, stream>>>(h2, wm, bm, h3);
    // wb mix + block-min + softmax
    final_k<<<90, 128, 0, stream>>>(h3, wb, bb, (float*)d_out);
}

// Round 2
// 1230.498 us; speedup vs baseline: 1.3074x; 1.3074x over previous
//
#include <hip/hip_runtime.h>
#include <math.h>

#define HO 15
#define LBL 21
#define MIX 5
#define LM 105   // LBL*MIX

__device__ __forceinline__ float max4(float a, float b, float c, float d) {
    return fmaxf(fmaxf(a, b), fmaxf(c, d));
}

// ---------------- 3x3 conv (pad 1), relu, optional 2x2-maxpool-on-read ----------------
// POOL=1: input is Hi x Hi = H x H. POOL=2: input stored Hi x Hi, conv runs on
// pooled H x H view (H = floor(Hi/2)), each read takes max of a 2x2 patch.
template <int POOL>
__global__ void conv3x3(const float* __restrict__ in, const float* __restrict__ w,
                        const float* __restrict__ bias, float* __restrict__ out,
                        int Cin, int Cout, int Hi, int H) {
    int idx = blockIdx.x * blockDim.x + threadIdx.x;
    int total = 2 * Cout * H * H;
    if (idx >= total) return;
    int x = idx % H; int t = idx / H;
    int y = t % H; t /= H;
    int o = t % Cout; int b = t / Cout;
    const float* ip = in + (size_t)b * Cin * Hi * Hi;
    const float* wp = w + (size_t)o * Cin * 9;
    float acc = bias[o];
    for (int c = 0; c < Cin; ++c) {
        const float* ic = ip + (size_t)c * Hi * Hi;
        const float* wc = wp + c * 9;
#pragma unroll
        for (int ky = 0; ky < 3; ++ky) {
            int yy = y + ky - 1;
            if (yy < 0 || yy >= H) continue;
#pragma unroll
            for (int kx = 0; kx < 3; ++kx) {
                int xx = x + kx - 1;
                if (xx < 0 || xx >= H) continue;
                float val;
                if (POOL == 1) {
                    val = ic[yy * Hi + xx];
                } else {
                    const float* q = ic + (2 * yy) * Hi + 2 * xx;
                    val = max4(q[0], q[1], q[Hi], q[Hi + 1]);
                }
                acc += val * wc[ky * 3 + kx];
            }
        }
    }
    out[idx] = fmaxf(acc, 0.f);
}

// ---------------- matvec with strided weight tap, optional pooled input ----------------
// out[b,o] = act( sum_c w[(o*Cin+c)*S + F] * in_c + bias[o] )
// POOL=2: input is [b][c][3][3], in_c = max of the single valid 2x2 window.
// ACT: 0=none, 1=relu, 2=sigmoid. One 64-lane wave per output.
template <int ACT, int POOL>
__global__ void matvec(const float* __restrict__ in, const float* __restrict__ w,
                       const float* __restrict__ bias, float* __restrict__ out,
                       int Cin, int Cout, int S, int F) {
    int wid = (blockIdx.x * blockDim.x + threadIdx.x) >> 6;
    int lane = threadIdx.x & 63;
    if (wid >= 2 * Cout) return;
    int b = wid / Cout, o = wid % Cout;
    float acc = 0.f;
    for (int c = lane; c < Cin; c += 64) {
        float iv;
        if (POOL == 2) {
            const float* q = in + ((size_t)b * Cin + c) * 9;
            iv = max4(q[0], q[1], q[3], q[4]);
        } else {
            iv = in[(size_t)b * Cin + c];
        }
        acc += w[((size_t)o * Cin + c) * S + F] * iv;
    }
#pragma unroll
    for (int off = 32; off; off >>= 1) acc += __shfl_xor(acc, off);
    if (lane == 0) {
        acc += bias[o];
        if (ACT == 1) acc = fmaxf(acc, 0.f);
        if (ACT == 2) acc = 1.f / (1.f + expf(-acc));
        out[(size_t)b * Cout + o] = acc;
    }
}

// ---------------- contiguous-row matvec (S==1), float4 vectorized ----------------
template <int ACT>
__global__ void matvec4(const float* __restrict__ in, const float* __restrict__ w,
                        const float* __restrict__ bias, float* __restrict__ out,
                        int Cin, int Cout) {
    int wid = (blockIdx.x * blockDim.x + threadIdx.x) >> 6;
    int lane = threadIdx.x & 63;
    if (wid >= 2 * Cout) return;
    int b = wid / Cout, o = wid % Cout;
    const float4* wp = (const float4*)(w + (size_t)o * Cin);
    const float4* ip = (const float4*)(in + (size_t)b * Cin);
    int n4 = Cin >> 2;
    float acc = 0.f;
    for (int k = lane; k < n4; k += 64) {
        float4 wv = wp[k];
        float4 iv = ip[k];
        acc += wv.x * iv.x + wv.y * iv.y + wv.z * iv.z + wv.w * iv.w;
    }
#pragma unroll
    for (int off = 32; off; off >>= 1) acc += __shfl_xor(acc, off);
    if (lane == 0) {
        acc += bias[o];
        if (ACT == 1) acc = fmaxf(acc, 0.f);
        if (ACT == 2) acc = 1.f / (1.f + expf(-acc));
        out[(size_t)b * Cout + o] = acc;
    }
}

// ---------------- locally-connected conv, collapsed ----------------
// h1[b,o,i,j] = sum_c v[b,c] * (14x14 window sum of wl[i,j,o,c]) + bl[o,i,j]
// One wave per (o,i,j). Per-lane window offsets hoisted out of the c-loop.
__global__ void localconv(const float* __restrict__ wl, const float* __restrict__ bl,
                          const float* __restrict__ v, float* __restrict__ h1) {
    int wid = (blockIdx.x * blockDim.x + threadIdx.x) >> 6;
    int lane = threadIdx.x & 63;
    if (wid >= LBL * HO * HO) return;
    int j = wid % HO; int t1 = wid / HO;
    int i = t1 % HO; int o = t1 / HO;
    int s0 = 25 - i, t0 = 25 - j;           // 14 valid taps each axis
    int e0 = lane, e1 = lane + 64, e2 = lane + 128, e3 = lane + 192;
    int off0 = (e0 / 14) * 50 + e0 % 14;
    int off1 = (e1 / 14) * 50 + e1 % 14;
    int off2 = (e2 / 14) * 50 + e2 % 14;
    int off3 = (e3 / 14) * 50 + e3 % 14;    // valid only for lane < 4
    size_t base_ij = ((size_t)(i * HO + j) * LBL + o) * LBL;
    const float* pij = wl + base_ij * 2500 + s0 * 50 + t0;
    float acc0 = 0.f, acc1 = 0.f;
    for (int c = 0; c < LBL; ++c) {
        const float* p = pij + (size_t)c * 2500;
        float part = p[off0] + p[off1] + p[off2];
        if (lane < 4) part += p[off3];
        acc0 += v[c] * part;
        acc1 += v[LBL + c] * part;
    }
#pragma unroll
    for (int off = 32; off; off >>= 1) {
        acc0 += __shfl_xor(acc0, off);
        acc1 += __shfl_xor(acc1, off);
    }
    if (lane == 0) {
        float bv = bl[(o * HO + i) * HO + j];
        h1[((0 * LBL + o) * HO + i) * HO + j] = acc0 + bv;
        h1[((1 * LBL + o) * HO + i) * HO + j] = acc1 + bv;
    }
}

// ---------------- fused: wa channel mix + conv3d-collapsed 9x9 conv ----------------
// Block per (b,o): stages h1, wa, and the wm[...,10] slice in LDS, computes the
// wa mix (h2) in LDS, then the 9x9 conv. h3[b,o,i,j].
__global__ void conv9x9_fused(const float* __restrict__ h1, const float* __restrict__ wa,
                              const float* __restrict__ ba, const float* __restrict__ wm,
                              const float* __restrict__ bm, float* __restrict__ h3) {
    __shared__ float s1[LBL * HO * HO];   // h1 for this image
    __shared__ float s2[LBL * HO * HO];   // h2 = wa-mix of h1
    __shared__ float sw[LBL * 81];        // wm slice for this o
    __shared__ float swa[LBL * LBL];
    int b = blockIdx.x / LM, o = blockIdx.x % LM;
    int tid = threadIdx.x;
    for (int k = tid; k < LBL * HO * HO; k += 256)
        s1[k] = h1[(size_t)b * LBL * HO * HO + k];
    for (int k = tid; k < LBL * LBL; k += 256)
        swa[k] = wa[k];
    for (int k = tid; k < LBL * 81; k += 256)
        sw[k] = wm[((size_t)o * (LBL * 81) + k) * LBL + 10];
    __syncthreads();
    for (int k = tid; k < LBL * HO * HO; k += 256) {
        int c = k / (HO * HO), pix = k % (HO * HO);
        float acc = ba[c];
        for (int c2 = 0; c2 < LBL; ++c2)
            acc += swa[c * LBL + c2] * s1[c2 * (HO * HO) + pix];
        s2[k] = acc;
    }
    __syncthreads();
    if (tid >= HO * HO) return;
    int i = tid / HO, j = tid % HO;
    float acc = bm[o];
    for (int c = 0; c < LBL; ++c) {
        const float* wp = sw + c * 81;
        const float* hp = s2 + c * (HO * HO);
#pragma unroll
        for (int di = 0; di < 9; ++di) {
            int y = i + di - 4;
            if (y < 0 || y >= HO) continue;
#pragma unroll
            for (int dj = 0; dj < 9; ++dj) {
                int x = j + dj - 4;
                if (x < 0 || x >= HO) continue;
                acc += hp[y * HO + x] * wp[di * 9 + dj];
            }
        }
    }
    h3[((size_t)b * LM + o) * (HO * HO) + tid] = acc;
}

// ---------------- wb mix + block-min(5) + softmax(105) ----------------
__global__ void final_k(const float* __restrict__ h3, const float* __restrict__ wbw,
                        const float* __restrict__ bbv, float* __restrict__ out) {
    __shared__ float sv[LM];
    __shared__ float s_mx, s_sum;
    int blk = blockIdx.x;
    int k = blk % 3; int t = blk / 3; int i = t % HO; int b = t / HO;
    int o = threadIdx.x;
    if (o < LM) {
        float mn = 3.4e38f;
        for (int mm = 0; mm < MIX; ++mm) {
            int j = mm * 3 + k;
            float acc = bbv[o];
            const float* hp = h3 + (size_t)b * LM * HO * HO + i * HO + j;
            const float* wp = wbw + o * LM;
            for (int c = 0; c < LM; ++c) acc += wp[c] * hp[(size_t)c * HO * HO];
            mn = fminf(mn, acc);
        }
        sv[o] = mn;
    }
    __syncthreads();
    if (threadIdx.x < 64) {
        int lane = threadIdx.x;
        float m = -3.4e38f;
        for (int c = lane; c < LM; c += 64) m = fmaxf(m, sv[c]);
#pragma unroll
        for (int off = 32; off; off >>= 1) m = fmaxf(m, __shfl_xor(m, off));
        if (lane == 0) s_mx = m;
    }
    __syncthreads();
    if (o < LM) sv[o] = expf(sv[o] - s_mx);
    __syncthreads();
    if (threadIdx.x < 64) {
        int lane = threadIdx.x;
        float s = 0.f;
        for (int c = lane; c < LM; c += 64) s += sv[c];
#pragma unroll
        for (int off = 32; off; off >>= 1) s += __shfl_xor(s, off);
        if (lane == 0) s_sum = s;
    }
    __syncthreads();
    if (o < LM) out[(((size_t)b * LM + o) * HO + i) * 3 + k] = sv[o] / s_sum;
}

extern "C" void kernel_launch(void* const* d_in, const int* in_sizes, int n_in,
                              void* d_out, int out_size, void* d_ws, size_t ws_size,
                              hipStream_t stream) {
    const float* x = (const float*)d_in[0];
    const float* w[14]; const float* bs[14];
    for (int i = 1; i <= 13; ++i) {
        w[i]  = (const float*)d_in[2 * i - 1];
        bs[i] = (const float*)d_in[2 * i];
    }
    const float* wf1 = (const float*)d_in[27]; const float* bf1 = (const float*)d_in[28];
    const float* wf2 = (const float*)d_in[29]; const float* bf2 = (const float*)d_in[30];
    const float* wf3 = (const float*)d_in[31]; const float* bf3 = (const float*)d_in[32];
    const float* wl  = (const float*)d_in[33]; const float* bl  = (const float*)d_in[34];
    const float* wa  = (const float*)d_in[35]; const float* ba  = (const float*)d_in[36];
    const float* wm  = (const float*)d_in[37]; const float* bm  = (const float*)d_in[38];
    const float* wb  = (const float*)d_in[39]; const float* bb  = (const float*)d_in[40];

    float* wsf = (float*)d_ws;
    float* A  = wsf;                   // 32768
    float* B  = wsf + 32768;           // 32768
    float* v  = wsf + 65536;           // 42 sigmoid scalars
    float* h1 = wsf + 65664;           // 9450
    float* h3 = wsf + 75136;           // 47250

    auto cdiv = [](int a, int b) { return (a + b - 1) / b; };

    // VGG trunk; maxpools folded into the consumer's input read (POOL=2)
    conv3x3<1><<<cdiv(2 * 64 * 196, 256), 256, 0, stream>>>(x, w[1], bs[1], A, 3, 64, 14, 14);
    conv3x3<1><<<cdiv(2 * 64 * 196, 256), 256, 0, stream>>>(A, w[2], bs[2], B, 64, 64, 14, 14);
    conv3x3<2><<<cdiv(2 * 128 * 49, 256), 256, 0, stream>>>(B, w[3], bs[3], A, 64, 128, 14, 7);
    conv3x3<1><<<cdiv(2 * 128 * 49, 256), 256, 0, stream>>>(A, w[4], bs[4], B, 128, 128, 7, 7);
    conv3x3<2><<<cdiv(2 * 256 * 9, 256), 256, 0, stream>>>(B, w[5], bs[5], A, 128, 256, 7, 3);
    conv3x3<1><<<cdiv(2 * 256 * 9, 256), 256, 0, stream>>>(A, w[6], bs[6], B, 256, 256, 3, 3);
    conv3x3<1><<<cdiv(2 * 256 * 9, 256), 256, 0, stream>>>(B, w[7], bs[7], A, 256, 256, 3, 3);

    // 1x1-spatial layers: center-tap matvecs; first one pools 3x3 -> 1x1 on read
    matvec<1, 2><<<cdiv(2 * 512, 4), 256, 0, stream>>>(A, w[8],  bs[8],  B, 256, 512, 9, 4);
    matvec<1, 1><<<cdiv(2 * 512, 4), 256, 0, stream>>>(B, w[9],  bs[9],  A, 512, 512, 9, 4);
    matvec<1, 1><<<cdiv(2 * 512, 4), 256, 0, stream>>>(A, w[10], bs[10], B, 512, 512, 9, 4);
    matvec<1, 1><<<cdiv(2 * 512, 4), 256, 0, stream>>>(B, w[11], bs[11], A, 512, 512, 9, 4);
    matvec<1, 1><<<cdiv(2 * 512, 4), 256, 0, stream>>>(A, w[12], bs[12], B, 512, 512, 9, 4);
    matvec<1, 1><<<cdiv(2 * 512, 4), 256, 0, stream>>>(B, w[13], bs[13], A, 512, 512, 9, 4);
    matvec<1, 1><<<cdiv(2 * 4096, 4), 256, 0, stream>>>(A, wf1, bf1, B, 512, 4096, 49, 24);
    matvec4<1><<<cdiv(2 * 4096, 4), 256, 0, stream>>>(B, wf2, bf2, A, 4096, 4096);
    matvec4<2><<<cdiv(2 * LBL, 4), 256, 0, stream>>>(A, wf3, bf3, v, 4096, LBL);

    // collapsed locally-connected conv
    localconv<<<cdiv(LBL * HO * HO, 4), 256, 0, stream>>>(wl, bl, v, h1);
    // fused wa mix + 9x9 conv (conv3d slice kw=10)
    conv9x9_fused<<<2 * LM, 256, 0, stream>>>(h1, wa, ba, wm, bm, h3);
    // wb mix + block-min + softmax
    final_k<<<90, 128, 0, stream>>>(h3, wb, bb, (float*)d_out);
}